// Round 1
// 295.112 us; speedup vs baseline: 1.1148x; 1.1148x over previous
//
#include <hip/hip_runtime.h>

#define TSEQ 4096
#define CDIM 1024
#define DHEAD 64

typedef __bf16 bf16x8 __attribute__((ext_vector_type(8)));
typedef float f32x4 __attribute__((ext_vector_type(4)));

// ---------------- Projection: out[m,n] = sum_c emb[m,c] * W[n,c] ----------------
// LDS-staged: per 128-col K-chunk, stage emb tile (64 rows) and the full W slice
// (64 rows) as bf16 via row-contiguous 1KB global loads.
// grid.x = M/64, grid.y = 3 (q,k,v). Q,K stored [B*T,64] bf16,
// V stored transposed Vt[b][64][T] bf16 so attention PV B-frags are contiguous.
#define KCHUNK 128          // f32 cols per chunk
#define NCHUNK (CDIM / KCHUNK)
#define LSTRIDE 136         // 128 + 8 pad (keeps 16B alignment: 272B = 17*16)

__global__ __launch_bounds__(256) void proj_kernel(
    const float* __restrict__ qe, const float* __restrict__ ke,
    const float* __restrict__ ve, const float* __restrict__ wq,
    const float* __restrict__ wk, const float* __restrict__ wv,
    __bf16* __restrict__ Qo, __bf16* __restrict__ Ko, __bf16* __restrict__ Vto)
{
  __shared__ __bf16 Al[64][LSTRIDE];
  __shared__ __bf16 Wl[64][LSTRIDE];

  const int pid = blockIdx.y;
  const float* __restrict__ emb = (pid == 0) ? qe : ((pid == 1) ? ke : ve);
  const float* __restrict__ W   = (pid == 0) ? wq : ((pid == 1) ? wk : wv);
  const int wave = threadIdx.x >> 6;
  const int lane = threadIdx.x & 63;
  const int g = lane >> 4, c = lane & 15;
  const int bm0 = blockIdx.x * 64;

  const int lr = lane >> 5;          // row parity within a 2-row staging inst
  const int lc = (lane & 31) * 4;    // f32 col within chunk (also bf16 col)

  f32x4 acc[4];
#pragma unroll
  for (int n = 0; n < 4; ++n) acc[n] = (f32x4){0.f, 0.f, 0.f, 0.f};

  for (int ch = 0; ch < NCHUNK; ++ch) {
    const int k0 = ch * KCHUNK;
    __syncthreads();  // prior chunk's fragment reads done before overwrite
    // stage: each wave covers rows [wave*16, wave*16+16), 2 rows per inst
#pragma unroll
    for (int j = 0; j < 8; ++j) {
      const int row = wave * 16 + 2 * j + lr;
      f32x4 av = *(const f32x4*)(emb + (size_t)(bm0 + row) * CDIM + k0 + lc);
      f32x4 wv4 = *(const f32x4*)(W + (size_t)row * CDIM + k0 + lc);
      short4 pa, pw;
      pa.x = __builtin_bit_cast(short, (__bf16)av[0]);
      pa.y = __builtin_bit_cast(short, (__bf16)av[1]);
      pa.z = __builtin_bit_cast(short, (__bf16)av[2]);
      pa.w = __builtin_bit_cast(short, (__bf16)av[3]);
      pw.x = __builtin_bit_cast(short, (__bf16)wv4[0]);
      pw.y = __builtin_bit_cast(short, (__bf16)wv4[1]);
      pw.z = __builtin_bit_cast(short, (__bf16)wv4[2]);
      pw.w = __builtin_bit_cast(short, (__bf16)wv4[3]);
      *(short4*)&Al[row][lc] = pa;
      *(short4*)&Wl[row][lc] = pw;
    }
    __syncthreads();
    // compute: wave's A rows = [wave*16, +16); all 64 W rows
#pragma unroll
    for (int ks = 0; ks < KCHUNK / 32; ++ks) {
      bf16x8 af = *(const bf16x8*)&Al[wave * 16 + c][ks * 32 + g * 8];
#pragma unroll
      for (int n = 0; n < 4; ++n) {
        bf16x8 wf = *(const bf16x8*)&Wl[n * 16 + c][ks * 32 + g * 8];
        acc[n] = __builtin_amdgcn_mfma_f32_16x16x32_bf16(af, wf, acc[n], 0, 0, 0);
      }
    }
  }

  const int m0 = bm0 + wave * 16;
  // C/D layout: col = lane&15 (=c -> n*16+c), row = (lane>>4)*4 + reg (= m0+4g+r)
  if (pid < 2) {
    __bf16* __restrict__ dst = (pid == 0) ? Qo : Ko;
#pragma unroll
    for (int n = 0; n < 4; ++n)
#pragma unroll
      for (int r = 0; r < 4; ++r)
        dst[(size_t)(m0 + g * 4 + r) * DHEAD + n * 16 + c] = (__bf16)acc[n][r];
  } else {
    // Vt[b][v][t]: regs 0..3 are 4 consecutive t -> pack one 8B store
    const int t0 = m0 + g * 4;
    const int bb = t0 >> 12;        // 4096 rows per batch, blocks never straddle
    const int tl = t0 & (TSEQ - 1);
#pragma unroll
    for (int n = 0; n < 4; ++n) {
      const int v = n * 16 + c;
      ushort4 pk;
      pk.x = __builtin_bit_cast(unsigned short, (__bf16)acc[n][0]);
      pk.y = __builtin_bit_cast(unsigned short, (__bf16)acc[n][1]);
      pk.z = __builtin_bit_cast(unsigned short, (__bf16)acc[n][2]);
      pk.w = __builtin_bit_cast(unsigned short, (__bf16)acc[n][3]);
      *(ushort4*)(Vto + ((size_t)bb * DHEAD + v) * TSEQ + tl) = pk;
    }
  }
}

// ---------------- Causal flash attention, static-max softmax ----------------
// One block = 16 q-rows, EIGHT waves split the s-tiles (st = wave, wave+8, ...).
// Rationale (rocprof): previous 2-wave version was latency-bound —
// MfmaUtil 3.2%, VALUBusy 7.7%, Occupancy 11.95%, HBM 2.3% of peak. K/V are
// L2-resident (FETCH 17MB), so the fix is TLP: 8 waves/block, LDS ~51KB ->
// 3 blocks/CU -> 24 resident waves/CU (vs ~3.8), VGPR stays ~50 (loads inline).
// Static m=0 is safe: |scores| < ~1 after 1/32 scale, exp2 cannot overflow.
// Row-sum l computed with a ones-vector MFMA (lands in same C-layout rows as O).
// OUTPUT IS FLOAT32 (reference output dtype).
#define NWAVE 8

__global__ __launch_bounds__(512) void attn_kernel(
    const __bf16* __restrict__ Q, const __bf16* __restrict__ K,
    const __bf16* __restrict__ Vt, float* __restrict__ out)
{
  __shared__ __bf16 Plds[NWAVE][16][72];   // per-wave P (C-layout -> A-layout round trip)
  __shared__ float Om[NWAVE][16][65];      // per-wave partial O for the merge
  __shared__ float La[NWAVE][16];          // per-wave partial row-sums

  const int b = blockIdx.y;
  const int tile = (int)gridDim.x - 1 - (int)blockIdx.x;  // big tiles first
  const int q0 = tile * 16;
  const int wave = threadIdx.x >> 6;
  const int lane = threadIdx.x & 63;
  const int g = lane >> 4, c = lane & 15;

  const __bf16* Qb = Q + (size_t)b * TSEQ * DHEAD;
  const __bf16* Kb = K + (size_t)b * TSEQ * DHEAD;
  const __bf16* Vb = Vt + (size_t)b * DHEAD * TSEQ;

  bf16x8 aq0 = *(const bf16x8*)(Qb + (size_t)(q0 + c) * DHEAD + g * 8);
  bf16x8 aq1 = *(const bf16x8*)(Qb + (size_t)(q0 + c) * DHEAD + 32 + g * 8);

  bf16x8 ones;
#pragma unroll
  for (int j = 0; j < 8; ++j) ones[j] = (__bf16)1.0f;

  f32x4 o[4];
#pragma unroll
  for (int n = 0; n < 4; ++n) o[n] = (f32x4){0.f, 0.f, 0.f, 0.f};
  f32x4 lacc = (f32x4){0.f, 0.f, 0.f, 0.f};

  const float kScale = 0.04508422f;  // (1/32) * log2(e)
  const int nt = (q0 + 16 + 63) >> 6;

  for (int st = wave; st < nt; st += NWAVE) {
    const int s0 = st * 64;
    // S = Q K^T  (16 q x 64 s per wave)
    f32x4 s[4];
#pragma unroll
    for (int n = 0; n < 4; ++n) {
      const __bf16* kp = Kb + (size_t)(s0 + n * 16 + c) * DHEAD + g * 8;
      bf16x8 b0 = *(const bf16x8*)(kp);
      bf16x8 b1 = *(const bf16x8*)(kp + 32);
      f32x4 z = (f32x4){0.f, 0.f, 0.f, 0.f};
      z = __builtin_amdgcn_mfma_f32_16x16x32_bf16(aq0, b0, z, 0, 0, 0);
      s[n] = __builtin_amdgcn_mfma_f32_16x16x32_bf16(aq1, b1, z, 0, 0, 0);
    }
    // mask + exp2 (static max), write P to LDS in [q][s] layout
#pragma unroll
    for (int n = 0; n < 4; ++n) {
      const int sidx = s0 + n * 16 + c;
#pragma unroll
      for (int r = 0; r < 4; ++r) {
        const int qidx = q0 + g * 4 + r;
        float p = (sidx <= qidx) ? __builtin_amdgcn_exp2f(s[n][r] * kScale) : 0.f;
        Plds[wave][g * 4 + r][n * 16 + c] = (__bf16)p;
      }
    }
    // A-frags of P: lane reads row c, 8 contiguous s per k-chunk.
    // Same-wave DS ops are processed in order; compiler handles lgkmcnt.
    bf16x8 p0 = *(const bf16x8*)(&Plds[wave][c][g * 8]);
    bf16x8 p1 = *(const bf16x8*)(&Plds[wave][c][32 + g * 8]);
    // l += rowsum(P) via ones MFMA (result rows match O accumulator rows)
    lacc = __builtin_amdgcn_mfma_f32_16x16x32_bf16(p0, ones, lacc, 0, 0, 0);
    lacc = __builtin_amdgcn_mfma_f32_16x16x32_bf16(p1, ones, lacc, 0, 0, 0);
    // O += P V  (Vt gives contiguous B-frags)
#pragma unroll
    for (int n = 0; n < 4; ++n) {
      const __bf16* vp = Vb + (size_t)(n * 16 + c) * TSEQ + s0 + g * 8;
      bf16x8 v0 = *(const bf16x8*)(vp);
      bf16x8 v1 = *(const bf16x8*)(vp + 32);
      o[n] = __builtin_amdgcn_mfma_f32_16x16x32_bf16(p0, v0, o[n], 0, 0, 0);
      o[n] = __builtin_amdgcn_mfma_f32_16x16x32_bf16(p1, v1, o[n], 0, 0, 0);
    }
  }

  // write per-wave partials (static max => plain sums merge)
#pragma unroll
  for (int n = 0; n < 4; ++n)
#pragma unroll
    for (int r = 0; r < 4; ++r)
      Om[wave][g * 4 + r][n * 16 + c] = o[n][r];
  if (c == 0) {
#pragma unroll
    for (int r = 0; r < 4; ++r) La[wave][g * 4 + r] = lacc[r];
  }
  __syncthreads();

  // f32 output: 512 threads x (1 row x 2 cols) = 16 rows x 64 cols
  const int tid = threadIdx.x;
  const int q = tid >> 5;
  const int c2 = (tid & 31) * 2;
  float l = 0.f;
#pragma unroll
  for (int w = 0; w < NWAVE; ++w) l += La[w][q];
  float s0 = 0.f, s1 = 0.f;
#pragma unroll
  for (int w = 0; w < NWAVE; ++w) {
    s0 += Om[w][q][c2];
    s1 += Om[w][q][c2 + 1];
  }
  const float inv = 1.0f / l;
  float2 r;
  r.x = s0 * inv;
  r.y = s1 * inv;
  *(float2*)(out + ((size_t)b * TSEQ + q0 + q) * DHEAD + c2) = r;
}

extern "C" void kernel_launch(void* const* d_in, const int* in_sizes, int n_in,
                              void* d_out, int out_size, void* d_ws, size_t ws_size,
                              hipStream_t stream) {
  const float* qe = (const float*)d_in[0];
  const float* ke = (const float*)d_in[1];
  const float* ve = (const float*)d_in[2];
  const float* wq = (const float*)d_in[3];
  const float* wk = (const float*)d_in[4];
  const float* wv = (const float*)d_in[5];

  __bf16* Qw  = (__bf16*)d_ws;
  __bf16* Kw  = Qw + (size_t)4 * TSEQ * DHEAD;
  __bf16* Vtw = Kw + (size_t)4 * TSEQ * DHEAD;

  dim3 g1(4 * TSEQ / 64, 3), b1(256);
  proj_kernel<<<g1, b1, 0, stream>>>(qe, ke, ve, wq, wk, wv, Qw, Kw, Vtw);

  dim3 g2(TSEQ / 16, 4), b2(512);
  attn_kernel<<<g2, b2, 0, stream>>>(Qw, Kw, Vtw, (float*)d_out);
}

// Round 2
// 286.090 us; speedup vs baseline: 1.1500x; 1.0315x over previous
//
#include <hip/hip_runtime.h>

#define TSEQ 4096
#define CDIM 1024
#define DHEAD 64

typedef __bf16 bf16x8 __attribute__((ext_vector_type(8)));
typedef float f32x4 __attribute__((ext_vector_type(4)));

// ---------------- Projection: out[m,n] = sum_c emb[m,c] * W[n,c] ----------------
// LDS-staged with a REGISTER PREFETCH PIPELINE. rocprof r1: proj was 134us with
// VGPR=52 -> compiler serialized staging into load->vmcnt(0)->cvt->ds_write per
// 2-row group (64 full-latency waits per block). Fix: batch all 16 loads of a
// chunk into unrolled reg arrays (one amortized wait) and issue chunk ch+1's
// loads right after chunk ch's LDS writes, so HBM latency hides under the MFMA
// phase. LDS single-buffered (34.8KB -> 4 blocks/CU), barriers unchanged.
// grid.x = M/64, grid.y = 3 (q,k,v). Q,K stored [B*T,64] bf16,
// V stored transposed Vt[b][64][T] bf16 so attention PV B-frags are contiguous.
#define KCHUNK 128          // f32 cols per chunk
#define NCHUNK (CDIM / KCHUNK)
#define LSTRIDE 136         // 128 + 8 pad (keeps 16B alignment: 272B = 17*16)

__global__ __launch_bounds__(256) void proj_kernel(
    const float* __restrict__ qe, const float* __restrict__ ke,
    const float* __restrict__ ve, const float* __restrict__ wq,
    const float* __restrict__ wk, const float* __restrict__ wv,
    __bf16* __restrict__ Qo, __bf16* __restrict__ Ko, __bf16* __restrict__ Vto)
{
  __shared__ __bf16 Al[64][LSTRIDE];
  __shared__ __bf16 Wl[64][LSTRIDE];

  const int pid = blockIdx.y;
  const float* __restrict__ emb = (pid == 0) ? qe : ((pid == 1) ? ke : ve);
  const float* __restrict__ W   = (pid == 0) ? wq : ((pid == 1) ? wk : wv);
  const int wave = threadIdx.x >> 6;
  const int lane = threadIdx.x & 63;
  const int g = lane >> 4, c = lane & 15;
  const int bm0 = blockIdx.x * 64;

  const int lr = lane >> 5;          // row parity within a 2-row staging inst
  const int lc = (lane & 31) * 4;    // f32 col within chunk (also bf16 col)

  // per-thread staging base pointers (row = wave*16 + 2j + lr)
  const float* __restrict__ ebase = emb + (size_t)(bm0 + wave * 16 + lr) * CDIM + lc;
  const float* __restrict__ wbase = W + (size_t)(wave * 16 + lr) * CDIM + lc;

  f32x4 acc[4];
#pragma unroll
  for (int n = 0; n < 4; ++n) acc[n] = (f32x4){0.f, 0.f, 0.f, 0.f};

  // prologue: batch-issue all 16 loads of chunk 0 (static indices -> registers)
  f32x4 ra[8], rw[8];
#pragma unroll
  for (int j = 0; j < 8; ++j) {
    ra[j] = *(const f32x4*)(ebase + (size_t)(2 * j) * CDIM);
    rw[j] = *(const f32x4*)(wbase + (size_t)(2 * j) * CDIM);
  }

  for (int ch = 0; ch < NCHUNK; ++ch) {
    __syncthreads();  // prior chunk's fragment reads done before overwrite
    // pack + write current chunk from registers (one amortized vmcnt wait)
#pragma unroll
    for (int j = 0; j < 8; ++j) {
      const int row = wave * 16 + 2 * j + lr;
      short4 pa, pw;
      pa.x = __builtin_bit_cast(short, (__bf16)ra[j][0]);
      pa.y = __builtin_bit_cast(short, (__bf16)ra[j][1]);
      pa.z = __builtin_bit_cast(short, (__bf16)ra[j][2]);
      pa.w = __builtin_bit_cast(short, (__bf16)ra[j][3]);
      pw.x = __builtin_bit_cast(short, (__bf16)rw[j][0]);
      pw.y = __builtin_bit_cast(short, (__bf16)rw[j][1]);
      pw.z = __builtin_bit_cast(short, (__bf16)rw[j][2]);
      pw.w = __builtin_bit_cast(short, (__bf16)rw[j][3]);
      *(short4*)&Al[row][lc] = pa;
      *(short4*)&Wl[row][lc] = pw;
    }
    // prefetch next chunk into the just-freed registers; latency hides under
    // this chunk's MFMA phase
    if (ch + 1 < NCHUNK) {
      const float* __restrict__ e2 = ebase + (size_t)(ch + 1) * KCHUNK;
      const float* __restrict__ w2 = wbase + (size_t)(ch + 1) * KCHUNK;
#pragma unroll
      for (int j = 0; j < 8; ++j) {
        ra[j] = *(const f32x4*)(e2 + (size_t)(2 * j) * CDIM);
        rw[j] = *(const f32x4*)(w2 + (size_t)(2 * j) * CDIM);
      }
    }
    __syncthreads();
    // compute: wave's A rows = [wave*16, +16); all 64 W rows
#pragma unroll
    for (int ks = 0; ks < KCHUNK / 32; ++ks) {
      bf16x8 af = *(const bf16x8*)&Al[wave * 16 + c][ks * 32 + g * 8];
#pragma unroll
      for (int n = 0; n < 4; ++n) {
        bf16x8 wf = *(const bf16x8*)&Wl[n * 16 + c][ks * 32 + g * 8];
        acc[n] = __builtin_amdgcn_mfma_f32_16x16x32_bf16(af, wf, acc[n], 0, 0, 0);
      }
    }
  }

  const int m0 = bm0 + wave * 16;
  // C/D layout: col = lane&15 (=c -> n*16+c), row = (lane>>4)*4 + reg (= m0+4g+r)
  if (pid < 2) {
    __bf16* __restrict__ dst = (pid == 0) ? Qo : Ko;
#pragma unroll
    for (int n = 0; n < 4; ++n)
#pragma unroll
      for (int r = 0; r < 4; ++r)
        dst[(size_t)(m0 + g * 4 + r) * DHEAD + n * 16 + c] = (__bf16)acc[n][r];
  } else {
    // Vt[b][v][t]: regs 0..3 are 4 consecutive t -> pack one 8B store
    const int t0 = m0 + g * 4;
    const int bb = t0 >> 12;        // 4096 rows per batch, blocks never straddle
    const int tl = t0 & (TSEQ - 1);
#pragma unroll
    for (int n = 0; n < 4; ++n) {
      const int v = n * 16 + c;
      ushort4 pk;
      pk.x = __builtin_bit_cast(unsigned short, (__bf16)acc[n][0]);
      pk.y = __builtin_bit_cast(unsigned short, (__bf16)acc[n][1]);
      pk.z = __builtin_bit_cast(unsigned short, (__bf16)acc[n][2]);
      pk.w = __builtin_bit_cast(unsigned short, (__bf16)acc[n][3]);
      *(ushort4*)(Vto + ((size_t)bb * DHEAD + v) * TSEQ + tl) = pk;
    }
  }
}

// ---------------- Causal flash attention, static-max softmax ----------------
// One block = 16 q-rows, EIGHT waves split the s-tiles (st = wave, wave+8, ...).
// r1: 8-wave TLP change took attn from 118us out of the top-5 (<131us).
// Static m=0 is safe: |scores| < ~1 after 1/32 scale, exp2 cannot overflow.
// Row-sum l computed with a ones-vector MFMA (lands in same C-layout rows as O).
// OUTPUT IS FLOAT32 (reference output dtype).
#define NWAVE 8

__global__ __launch_bounds__(512) void attn_kernel(
    const __bf16* __restrict__ Q, const __bf16* __restrict__ K,
    const __bf16* __restrict__ Vt, float* __restrict__ out)
{
  __shared__ __bf16 Plds[NWAVE][16][72];   // per-wave P (C-layout -> A-layout round trip)
  __shared__ float Om[NWAVE][16][65];      // per-wave partial O for the merge
  __shared__ float La[NWAVE][16];          // per-wave partial row-sums

  const int b = blockIdx.y;
  const int tile = (int)gridDim.x - 1 - (int)blockIdx.x;  // big tiles first
  const int q0 = tile * 16;
  const int wave = threadIdx.x >> 6;
  const int lane = threadIdx.x & 63;
  const int g = lane >> 4, c = lane & 15;

  const __bf16* Qb = Q + (size_t)b * TSEQ * DHEAD;
  const __bf16* Kb = K + (size_t)b * TSEQ * DHEAD;
  const __bf16* Vb = Vt + (size_t)b * DHEAD * TSEQ;

  bf16x8 aq0 = *(const bf16x8*)(Qb + (size_t)(q0 + c) * DHEAD + g * 8);
  bf16x8 aq1 = *(const bf16x8*)(Qb + (size_t)(q0 + c) * DHEAD + 32 + g * 8);

  bf16x8 ones;
#pragma unroll
  for (int j = 0; j < 8; ++j) ones[j] = (__bf16)1.0f;

  f32x4 o[4];
#pragma unroll
  for (int n = 0; n < 4; ++n) o[n] = (f32x4){0.f, 0.f, 0.f, 0.f};
  f32x4 lacc = (f32x4){0.f, 0.f, 0.f, 0.f};

  const float kScale = 0.04508422f;  // (1/32) * log2(e)
  const int nt = (q0 + 16 + 63) >> 6;

  for (int st = wave; st < nt; st += NWAVE) {
    const int s0 = st * 64;
    // S = Q K^T  (16 q x 64 s per wave)
    f32x4 s[4];
#pragma unroll
    for (int n = 0; n < 4; ++n) {
      const __bf16* kp = Kb + (size_t)(s0 + n * 16 + c) * DHEAD + g * 8;
      bf16x8 b0 = *(const bf16x8*)(kp);
      bf16x8 b1 = *(const bf16x8*)(kp + 32);
      f32x4 z = (f32x4){0.f, 0.f, 0.f, 0.f};
      z = __builtin_amdgcn_mfma_f32_16x16x32_bf16(aq0, b0, z, 0, 0, 0);
      s[n] = __builtin_amdgcn_mfma_f32_16x16x32_bf16(aq1, b1, z, 0, 0, 0);
    }
    // mask + exp2 (static max), write P to LDS in [q][s] layout
#pragma unroll
    for (int n = 0; n < 4; ++n) {
      const int sidx = s0 + n * 16 + c;
#pragma unroll
      for (int r = 0; r < 4; ++r) {
        const int qidx = q0 + g * 4 + r;
        float p = (sidx <= qidx) ? __builtin_amdgcn_exp2f(s[n][r] * kScale) : 0.f;
        Plds[wave][g * 4 + r][n * 16 + c] = (__bf16)p;
      }
    }
    // A-frags of P: lane reads row c, 8 contiguous s per k-chunk.
    // Same-wave DS ops are processed in order; compiler handles lgkmcnt.
    bf16x8 p0 = *(const bf16x8*)(&Plds[wave][c][g * 8]);
    bf16x8 p1 = *(const bf16x8*)(&Plds[wave][c][32 + g * 8]);
    // l += rowsum(P) via ones MFMA (result rows match O accumulator rows)
    lacc = __builtin_amdgcn_mfma_f32_16x16x32_bf16(p0, ones, lacc, 0, 0, 0);
    lacc = __builtin_amdgcn_mfma_f32_16x16x32_bf16(p1, ones, lacc, 0, 0, 0);
    // O += P V  (Vt gives contiguous B-frags)
#pragma unroll
    for (int n = 0; n < 4; ++n) {
      const __bf16* vp = Vb + (size_t)(n * 16 + c) * TSEQ + s0 + g * 8;
      bf16x8 v0 = *(const bf16x8*)(vp);
      bf16x8 v1 = *(const bf16x8*)(vp + 32);
      o[n] = __builtin_amdgcn_mfma_f32_16x16x32_bf16(p0, v0, o[n], 0, 0, 0);
      o[n] = __builtin_amdgcn_mfma_f32_16x16x32_bf16(p1, v1, o[n], 0, 0, 0);
    }
  }

  // write per-wave partials (static max => plain sums merge)
#pragma unroll
  for (int n = 0; n < 4; ++n)
#pragma unroll
    for (int r = 0; r < 4; ++r)
      Om[wave][g * 4 + r][n * 16 + c] = o[n][r];
  if (c == 0) {
#pragma unroll
    for (int r = 0; r < 4; ++r) La[wave][g * 4 + r] = lacc[r];
  }
  __syncthreads();

  // f32 output: 512 threads x (1 row x 2 cols) = 16 rows x 64 cols
  const int tid = threadIdx.x;
  const int q = tid >> 5;
  const int c2 = (tid & 31) * 2;
  float l = 0.f;
#pragma unroll
  for (int w = 0; w < NWAVE; ++w) l += La[w][q];
  float s0 = 0.f, s1 = 0.f;
#pragma unroll
  for (int w = 0; w < NWAVE; ++w) {
    s0 += Om[w][q][c2];
    s1 += Om[w][q][c2 + 1];
  }
  const float inv = 1.0f / l;
  float2 r;
  r.x = s0 * inv;
  r.y = s1 * inv;
  *(float2*)(out + ((size_t)b * TSEQ + q0 + q) * DHEAD + c2) = r;
}

extern "C" void kernel_launch(void* const* d_in, const int* in_sizes, int n_in,
                              void* d_out, int out_size, void* d_ws, size_t ws_size,
                              hipStream_t stream) {
  const float* qe = (const float*)d_in[0];
  const float* ke = (const float*)d_in[1];
  const float* ve = (const float*)d_in[2];
  const float* wq = (const float*)d_in[3];
  const float* wk = (const float*)d_in[4];
  const float* wv = (const float*)d_in[5];

  __bf16* Qw  = (__bf16*)d_ws;
  __bf16* Kw  = Qw + (size_t)4 * TSEQ * DHEAD;
  __bf16* Vtw = Kw + (size_t)4 * TSEQ * DHEAD;

  dim3 g1(4 * TSEQ / 64, 3), b1(256);
  proj_kernel<<<g1, b1, 0, stream>>>(qe, ke, ve, wq, wk, wv, Qw, Kw, Vtw);

  dim3 g2(TSEQ / 16, 4), b2(512);
  attn_kernel<<<g2, b2, 0, stream>>>(Qw, Kw, Vtw, (float*)d_out);
}

// Round 3
// 281.301 us; speedup vs baseline: 1.1696x; 1.0170x over previous
//
#include <hip/hip_runtime.h>

#define TSEQ 4096
#define CDIM 1024
#define DHEAD 64

typedef __bf16 bf16x8 __attribute__((ext_vector_type(8)));
typedef float f32x4 __attribute__((ext_vector_type(4)));

// ---------------- Projection: out[m,n] = sum_c emb[m,c] * W[n,c] ----------------
// LDS-staged with a REGISTER PREFETCH PIPELINE (r2: 134us -> below 83us).
// grid.x = M/64, grid.y = 3 (q,k,v). Q,K stored [B*T,64] bf16,
// V stored transposed Vt[b][64][T] bf16 so attention PV B-frags are contiguous.
#define KCHUNK 128          // f32 cols per chunk
#define NCHUNK (CDIM / KCHUNK)
#define LSTRIDE 136         // 128 + 8 pad (keeps 16B alignment: 272B = 17*16)

__global__ __launch_bounds__(256) void proj_kernel(
    const float* __restrict__ qe, const float* __restrict__ ke,
    const float* __restrict__ ve, const float* __restrict__ wq,
    const float* __restrict__ wk, const float* __restrict__ wv,
    __bf16* __restrict__ Qo, __bf16* __restrict__ Ko, __bf16* __restrict__ Vto)
{
  __shared__ __bf16 Al[64][LSTRIDE];
  __shared__ __bf16 Wl[64][LSTRIDE];

  const int pid = blockIdx.y;
  const float* __restrict__ emb = (pid == 0) ? qe : ((pid == 1) ? ke : ve);
  const float* __restrict__ W   = (pid == 0) ? wq : ((pid == 1) ? wk : wv);
  const int wave = threadIdx.x >> 6;
  const int lane = threadIdx.x & 63;
  const int g = lane >> 4, c = lane & 15;
  const int bm0 = blockIdx.x * 64;

  const int lr = lane >> 5;          // row parity within a 2-row staging inst
  const int lc = (lane & 31) * 4;    // f32 col within chunk (also bf16 col)

  // per-thread staging base pointers (row = wave*16 + 2j + lr)
  const float* __restrict__ ebase = emb + (size_t)(bm0 + wave * 16 + lr) * CDIM + lc;
  const float* __restrict__ wbase = W + (size_t)(wave * 16 + lr) * CDIM + lc;

  f32x4 acc[4];
#pragma unroll
  for (int n = 0; n < 4; ++n) acc[n] = (f32x4){0.f, 0.f, 0.f, 0.f};

  // prologue: batch-issue all 16 loads of chunk 0 (static indices -> registers)
  f32x4 ra[8], rw[8];
#pragma unroll
  for (int j = 0; j < 8; ++j) {
    ra[j] = *(const f32x4*)(ebase + (size_t)(2 * j) * CDIM);
    rw[j] = *(const f32x4*)(wbase + (size_t)(2 * j) * CDIM);
  }

  for (int ch = 0; ch < NCHUNK; ++ch) {
    __syncthreads();  // prior chunk's fragment reads done before overwrite
    // pack + write current chunk from registers (one amortized vmcnt wait)
#pragma unroll
    for (int j = 0; j < 8; ++j) {
      const int row = wave * 16 + 2 * j + lr;
      short4 pa, pw;
      pa.x = __builtin_bit_cast(short, (__bf16)ra[j][0]);
      pa.y = __builtin_bit_cast(short, (__bf16)ra[j][1]);
      pa.z = __builtin_bit_cast(short, (__bf16)ra[j][2]);
      pa.w = __builtin_bit_cast(short, (__bf16)ra[j][3]);
      pw.x = __builtin_bit_cast(short, (__bf16)rw[j][0]);
      pw.y = __builtin_bit_cast(short, (__bf16)rw[j][1]);
      pw.z = __builtin_bit_cast(short, (__bf16)rw[j][2]);
      pw.w = __builtin_bit_cast(short, (__bf16)rw[j][3]);
      *(short4*)&Al[row][lc] = pa;
      *(short4*)&Wl[row][lc] = pw;
    }
    // prefetch next chunk into the just-freed registers; latency hides under
    // this chunk's MFMA phase
    if (ch + 1 < NCHUNK) {
      const float* __restrict__ e2 = ebase + (size_t)(ch + 1) * KCHUNK;
      const float* __restrict__ w2 = wbase + (size_t)(ch + 1) * KCHUNK;
#pragma unroll
      for (int j = 0; j < 8; ++j) {
        ra[j] = *(const f32x4*)(e2 + (size_t)(2 * j) * CDIM);
        rw[j] = *(const f32x4*)(w2 + (size_t)(2 * j) * CDIM);
      }
    }
    __syncthreads();
    // compute: wave's A rows = [wave*16, +16); all 64 W rows
#pragma unroll
    for (int ks = 0; ks < KCHUNK / 32; ++ks) {
      bf16x8 af = *(const bf16x8*)&Al[wave * 16 + c][ks * 32 + g * 8];
#pragma unroll
      for (int n = 0; n < 4; ++n) {
        bf16x8 wf = *(const bf16x8*)&Wl[n * 16 + c][ks * 32 + g * 8];
        acc[n] = __builtin_amdgcn_mfma_f32_16x16x32_bf16(af, wf, acc[n], 0, 0, 0);
      }
    }
  }

  const int m0 = bm0 + wave * 16;
  // C/D layout: col = lane&15 (=c -> n*16+c), row = (lane>>4)*4 + reg (= m0+4g+r)
  if (pid < 2) {
    __bf16* __restrict__ dst = (pid == 0) ? Qo : Ko;
#pragma unroll
    for (int n = 0; n < 4; ++n)
#pragma unroll
      for (int r = 0; r < 4; ++r)
        dst[(size_t)(m0 + g * 4 + r) * DHEAD + n * 16 + c] = (__bf16)acc[n][r];
  } else {
    // Vt[b][v][t]: regs 0..3 are 4 consecutive t -> pack one 8B store
    const int t0 = m0 + g * 4;
    const int bb = t0 >> 12;        // 4096 rows per batch, blocks never straddle
    const int tl = t0 & (TSEQ - 1);
#pragma unroll
    for (int n = 0; n < 4; ++n) {
      const int v = n * 16 + c;
      ushort4 pk;
      pk.x = __builtin_bit_cast(unsigned short, (__bf16)acc[n][0]);
      pk.y = __builtin_bit_cast(unsigned short, (__bf16)acc[n][1]);
      pk.z = __builtin_bit_cast(unsigned short, (__bf16)acc[n][2]);
      pk.w = __builtin_bit_cast(unsigned short, (__bf16)acc[n][3]);
      *(ushort4*)(Vto + ((size_t)bb * DHEAD + v) * TSEQ + tl) = pk;
    }
  }
}

// ---------------- Causal flash attention, static-max softmax ----------------
// One block = 16 q-rows, 8 waves split the s-tiles. r2 rocprof: MfmaUtil 4.4%,
// VALUBusy 10.4%, Occ 30%, VGPR 52 -> still latency-bound; at VGPR=52 the
// compiler serialized each tile's chain (K wait -> QK -> exp -> DS round trip
// -> V wait -> PV). Fix: TWO INDEPENDENT s-tile chains per loop iteration
// (st and st+8). Both chains' K loads issue up front; V loads are hoisted so
// their latency hides under exp/DS; chain B's QK/loads issue while chain A
// waits on its DS round-trip. DS in-order + P-buffer aliasing (B's writes
// alias A's reads) give ordering without barriers.
// Static m=0 is safe: |scores| < ~1 after 1/32 scale, exp2 cannot overflow.
// Row-sum l computed with a ones-vector MFMA (lands in same C-layout rows as O).
// OUTPUT IS FLOAT32 (reference output dtype).
#define NWAVE 8

__global__ __launch_bounds__(512) void attn_kernel(
    const __bf16* __restrict__ Q, const __bf16* __restrict__ K,
    const __bf16* __restrict__ Vt, float* __restrict__ out)
{
  __shared__ __bf16 Plds[NWAVE][16][72];   // per-wave P (C-layout -> A-layout round trip)
  __shared__ float Om[NWAVE][16][65];      // per-wave partial O for the merge
  __shared__ float La[NWAVE][16];          // per-wave partial row-sums

  const int b = blockIdx.y;
  const int tile = (int)gridDim.x - 1 - (int)blockIdx.x;  // big tiles first
  const int q0 = tile * 16;
  const int wave = threadIdx.x >> 6;
  const int lane = threadIdx.x & 63;
  const int g = lane >> 4, c = lane & 15;

  const __bf16* Qb = Q + (size_t)b * TSEQ * DHEAD;
  const __bf16* Kb = K + (size_t)b * TSEQ * DHEAD;
  const __bf16* Vb = Vt + (size_t)b * DHEAD * TSEQ;

  bf16x8 aq0 = *(const bf16x8*)(Qb + (size_t)(q0 + c) * DHEAD + g * 8);
  bf16x8 aq1 = *(const bf16x8*)(Qb + (size_t)(q0 + c) * DHEAD + 32 + g * 8);

  bf16x8 ones;
#pragma unroll
  for (int j = 0; j < 8; ++j) ones[j] = (__bf16)1.0f;

  f32x4 o[4];
#pragma unroll
  for (int n = 0; n < 4; ++n) o[n] = (f32x4){0.f, 0.f, 0.f, 0.f};
  f32x4 lacc = (f32x4){0.f, 0.f, 0.f, 0.f};

  const float kScale = 0.04508422f;  // (1/32) * log2(e)
  const int nt = (q0 + 16 + 63) >> 6;

  for (int st = wave; st < nt; st += 2 * NWAVE) {
    const int s0A = st * 64;
    const int stB = st + NWAVE;
    const bool hasB = stB < nt;              // wave-uniform
    const int s0B = stB * 64;

    // ---- issue BOTH chains' K loads up front (16 loads in flight) ----
    bf16x8 ka0[4], ka1[4], kb0[4], kb1[4];
#pragma unroll
    for (int n = 0; n < 4; ++n) {
      const __bf16* kp = Kb + (size_t)(s0A + n * 16 + c) * DHEAD + g * 8;
      ka0[n] = *(const bf16x8*)(kp);
      ka1[n] = *(const bf16x8*)(kp + 32);
    }
    if (hasB) {
#pragma unroll
      for (int n = 0; n < 4; ++n) {
        const __bf16* kp = Kb + (size_t)(s0B + n * 16 + c) * DHEAD + g * 8;
        kb0[n] = *(const bf16x8*)(kp);
        kb1[n] = *(const bf16x8*)(kp + 32);
      }
    }

    // ---- chain A: QK ----
    f32x4 sA[4];
#pragma unroll
    for (int n = 0; n < 4; ++n) {
      f32x4 z = (f32x4){0.f, 0.f, 0.f, 0.f};
      z = __builtin_amdgcn_mfma_f32_16x16x32_bf16(aq0, ka0[n], z, 0, 0, 0);
      sA[n] = __builtin_amdgcn_mfma_f32_16x16x32_bf16(aq1, ka1[n], z, 0, 0, 0);
    }
    // ---- hoisted V loads A (latency hides under exp/DS below) ----
    bf16x8 va0[4], va1[4];
#pragma unroll
    for (int n = 0; n < 4; ++n) {
      const __bf16* vp = Vb + (size_t)(n * 16 + c) * TSEQ + s0A + g * 8;
      va0[n] = *(const bf16x8*)(vp);
      va1[n] = *(const bf16x8*)(vp + 32);
    }
    // ---- exp + DS-write A ----
#pragma unroll
    for (int n = 0; n < 4; ++n) {
      const int sidx = s0A + n * 16 + c;
#pragma unroll
      for (int r = 0; r < 4; ++r) {
        const int qidx = q0 + g * 4 + r;
        float p = (sidx <= qidx) ? __builtin_amdgcn_exp2f(sA[n][r] * kScale) : 0.f;
        Plds[wave][g * 4 + r][n * 16 + c] = (__bf16)p;
      }
    }

    // ---- chain B: QK (K arrived while A ran) + hoisted V loads B ----
    f32x4 sB[4];
    bf16x8 vb0[4], vb1[4];
    if (hasB) {
#pragma unroll
      for (int n = 0; n < 4; ++n) {
        f32x4 z = (f32x4){0.f, 0.f, 0.f, 0.f};
        z = __builtin_amdgcn_mfma_f32_16x16x32_bf16(aq0, kb0[n], z, 0, 0, 0);
        sB[n] = __builtin_amdgcn_mfma_f32_16x16x32_bf16(aq1, kb1[n], z, 0, 0, 0);
      }
#pragma unroll
      for (int n = 0; n < 4; ++n) {
        const __bf16* vp = Vb + (size_t)(n * 16 + c) * TSEQ + s0B + g * 8;
        vb0[n] = *(const bf16x8*)(vp);
        vb1[n] = *(const bf16x8*)(vp + 32);
      }
    }

    // ---- DS-read A, rowsum A ----
    bf16x8 p0A = *(const bf16x8*)(&Plds[wave][c][g * 8]);
    bf16x8 p1A = *(const bf16x8*)(&Plds[wave][c][32 + g * 8]);
    lacc = __builtin_amdgcn_mfma_f32_16x16x32_bf16(p0A, ones, lacc, 0, 0, 0);
    lacc = __builtin_amdgcn_mfma_f32_16x16x32_bf16(p1A, ones, lacc, 0, 0, 0);

    // ---- exp + DS-write B (aliases A's reads -> ordered after them) ----
    if (hasB) {
#pragma unroll
      for (int n = 0; n < 4; ++n) {
        const int sidx = s0B + n * 16 + c;
#pragma unroll
        for (int r = 0; r < 4; ++r) {
          const int qidx = q0 + g * 4 + r;
          float p = (sidx <= qidx) ? __builtin_amdgcn_exp2f(sB[n][r] * kScale) : 0.f;
          Plds[wave][g * 4 + r][n * 16 + c] = (__bf16)p;
        }
      }
    }

    // ---- PV A (V arrived during exp/DS) ----
#pragma unroll
    for (int n = 0; n < 4; ++n) {
      o[n] = __builtin_amdgcn_mfma_f32_16x16x32_bf16(p0A, va0[n], o[n], 0, 0, 0);
      o[n] = __builtin_amdgcn_mfma_f32_16x16x32_bf16(p1A, va1[n], o[n], 0, 0, 0);
    }

    // ---- DS-read B, rowsum B, PV B ----
    if (hasB) {
      bf16x8 p0B = *(const bf16x8*)(&Plds[wave][c][g * 8]);
      bf16x8 p1B = *(const bf16x8*)(&Plds[wave][c][32 + g * 8]);
      lacc = __builtin_amdgcn_mfma_f32_16x16x32_bf16(p0B, ones, lacc, 0, 0, 0);
      lacc = __builtin_amdgcn_mfma_f32_16x16x32_bf16(p1B, ones, lacc, 0, 0, 0);
#pragma unroll
      for (int n = 0; n < 4; ++n) {
        o[n] = __builtin_amdgcn_mfma_f32_16x16x32_bf16(p0B, vb0[n], o[n], 0, 0, 0);
        o[n] = __builtin_amdgcn_mfma_f32_16x16x32_bf16(p1B, vb1[n], o[n], 0, 0, 0);
      }
    }
  }

  // write per-wave partials (static max => plain sums merge)
#pragma unroll
  for (int n = 0; n < 4; ++n)
#pragma unroll
    for (int r = 0; r < 4; ++r)
      Om[wave][g * 4 + r][n * 16 + c] = o[n][r];
  if (c == 0) {
#pragma unroll
    for (int r = 0; r < 4; ++r) La[wave][g * 4 + r] = lacc[r];
  }
  __syncthreads();

  // f32 output: 512 threads x (1 row x 2 cols) = 16 rows x 64 cols
  const int tid = threadIdx.x;
  const int q = tid >> 5;
  const int c2 = (tid & 31) * 2;
  float l = 0.f;
#pragma unroll
  for (int w = 0; w < NWAVE; ++w) l += La[w][q];
  float s0 = 0.f, s1 = 0.f;
#pragma unroll
  for (int w = 0; w < NWAVE; ++w) {
    s0 += Om[w][q][c2];
    s1 += Om[w][q][c2 + 1];
  }
  const float inv = 1.0f / l;
  float2 r;
  r.x = s0 * inv;
  r.y = s1 * inv;
  *(float2*)(out + ((size_t)b * TSEQ + q0 + q) * DHEAD + c2) = r;
}

extern "C" void kernel_launch(void* const* d_in, const int* in_sizes, int n_in,
                              void* d_out, int out_size, void* d_ws, size_t ws_size,
                              hipStream_t stream) {
  const float* qe = (const float*)d_in[0];
  const float* ke = (const float*)d_in[1];
  const float* ve = (const float*)d_in[2];
  const float* wq = (const float*)d_in[3];
  const float* wk = (const float*)d_in[4];
  const float* wv = (const float*)d_in[5];

  __bf16* Qw  = (__bf16*)d_ws;
  __bf16* Kw  = Qw + (size_t)4 * TSEQ * DHEAD;
  __bf16* Vtw = Kw + (size_t)4 * TSEQ * DHEAD;

  dim3 g1(4 * TSEQ / 64, 3), b1(256);
  proj_kernel<<<g1, b1, 0, stream>>>(qe, ke, ve, wq, wk, wv, Qw, Kw, Vtw);

  dim3 g2(TSEQ / 16, 4), b2(512);
  attn_kernel<<<g2, b2, 0, stream>>>(Qw, Kw, Vtw, (float*)d_out);
}